// Round 17
// baseline (351.732 us; speedup 1.0000x reference)
//
#include <hip/hip_runtime.h>

#define ND 2048
#define NM 512
#define DIN 256
#define OC 128
#define NTOT 2560
#define NE 513      // slots per hyperedge

// Workspace float offsets. Dirty footprint ~1.6 MB (dirty ws slows the
// harness's 268 MB poison-fill — R14 evidence).
#define WS_PARTC 0                          // [256*256]
#define WS_PARTM (WS_PARTC + 256*256)       // [64*256]
#define WS_AHE   (WS_PARTM + 64*256)        // [2048]
#define WS_ANODE (WS_AHE + ND)              // [2560]
#define WS_CD    (WS_ANODE + NTOT)          // [2048]  C_d = M_d + ln(S_d)
#define WS_XLIN  (WS_CD + ND)               // [2560*128]; disease rows -> e in K2
#define WS_DIA   (WS_XLIN + NTOT*OC)        // [128]
#define WS_MED   (WS_DIA + OC)              // [128]

__device__ __forceinline__ float lrelu(float x) { return x > 0.f ? x : 0.2f * x; }

// ---------------------------------------------------------------------------
// K1: blocks 0..319: x_lin (8 rows) + a_node + mean partials.
//     blocks 320..383: w_e (redundant) + a_he (32 d's each).
__global__ void __launch_bounds__(256) K1(
        const float* __restrict__ c_emb, const float* __restrict__ m_emb,
        const float* __restrict__ W_gat, const float* __restrict__ att,
        const float* __restrict__ he_attr, float* __restrict__ ws) {
    const int b = blockIdx.x, t = threadIdx.x;
    if (b < 320) {
        __shared__ float row[8][DIN];    // 8 KB
        __shared__ float sA[8][OC];      // 4 KB
        const int d0 = b * 8;
#pragma unroll
        for (int p = 0; p < 4; ++p) {
            const int idx = p * 256 + t;           // 0..1023
            const int r = idx >> 7, c = idx & 127;
            const int d = d0 + r;
            const float* src = (d < ND) ? c_emb + (size_t)d * DIN
                                        : m_emb + (size_t)(d - ND) * DIN;
            const float2 u = ((const float2*)src)[c];
            row[r][2 * c]     = u.x;
            row[r][2 * c + 1] = u.y;
        }
        __syncthreads();
        {
            float pc = 0.f;
#pragma unroll
            for (int r = 0; r < 8; ++r) pc += row[r][t];
            if (b < 256) ws[WS_PARTC + b * 256 + t] = pc;
            else         ws[WS_PARTM + (b - 256) * 256 + t] = pc;
        }
        const int o = t & (OC - 1), h = t >> 7;
        float a0 = 0.f, a1 = 0.f, a2 = 0.f, a3 = 0.f;
        const float4* wr  = (const float4*)(W_gat + (size_t)o * DIN);
        const float4* r0v = (const float4*)(row[4 * h]);
        const float4* r1v = (const float4*)(row[4 * h + 1]);
        const float4* r2v = (const float4*)(row[4 * h + 2]);
        const float4* r3v = (const float4*)(row[4 * h + 3]);
#pragma unroll 4
        for (int v = 0; v < 64; ++v) {
            const float4 w  = wr[v];
            const float4 x0 = r0v[v], x1 = r1v[v], x2 = r2v[v], x3 = r3v[v];
            a0 = fmaf(x0.x, w.x, a0); a0 = fmaf(x0.y, w.y, a0);
            a0 = fmaf(x0.z, w.z, a0); a0 = fmaf(x0.w, w.w, a0);
            a1 = fmaf(x1.x, w.x, a1); a1 = fmaf(x1.y, w.y, a1);
            a1 = fmaf(x1.z, w.z, a1); a1 = fmaf(x1.w, w.w, a1);
            a2 = fmaf(x2.x, w.x, a2); a2 = fmaf(x2.y, w.y, a2);
            a2 = fmaf(x2.z, w.z, a2); a2 = fmaf(x2.w, w.w, a2);
            a3 = fmaf(x3.x, w.x, a3); a3 = fmaf(x3.y, w.y, a3);
            a3 = fmaf(x3.z, w.z, a3); a3 = fmaf(x3.w, w.w, a3);
        }
        float* xl = ws + WS_XLIN + (size_t)(d0 + 4 * h) * OC + o;
        xl[0 * OC] = a0; xl[1 * OC] = a1; xl[2 * OC] = a2; xl[3 * OC] = a3;
        const float at = att[o];
        sA[4 * h][o]     = a0 * at;
        sA[4 * h + 1][o] = a1 * at;
        sA[4 * h + 2][o] = a2 * at;
        sA[4 * h + 3][o] = a3 * at;
        __syncthreads();
#pragma unroll
        for (int st = 64; st >= 1; st >>= 1) {
            for (int idx = t; idx < 8 * st; idx += 256) {
                const int r = idx / st, i = idx - r * st;
                sA[r][i] += sA[r][i + st];
            }
            __syncthreads();
        }
        if (t < 8) ws[WS_ANODE + d0 + t] = sA[t][0];
    } else {
        __shared__ float satt[OC];
        __shared__ float we[DIN];
        const int q = b - 320;
        if (t < OC) satt[t] = att[OC + t];
        __syncthreads();
        float acc = 0.f;
#pragma unroll 8
        for (int o = 0; o < OC; ++o)
            acc = fmaf(W_gat[(size_t)o * DIN + t], satt[o], acc);
        we[t] = acc;
        __syncthreads();
        const int r = t >> 5, l = t & 31;
#pragma unroll
        for (int k = 0; k < 4; ++k) {
            const int d = q * 32 + k * 8 + r;
            const float* he = he_attr + (size_t)d * DIN;
            float ah = 0.f;
#pragma unroll
            for (int i = l; i < DIN; i += 32) ah = fmaf(he[i], we[i], ah);
#pragma unroll
            for (int m = 1; m < 32; m <<= 1) ah += __shfl_xor(ah, m, 32);
            if (l == 0) ws[WS_AHE + d] = ah;
        }
    }
}

// ---------------------------------------------------------------------------
// K2: blocks 0..255: softmax (8 d's) -> alpha, C_d; e in-place; disease dm half.
//     block 256: combine mean partials -> dia/med vectors.
__global__ void __launch_bounds__(256) K2(
        const float* __restrict__ W_conv, const float* __restrict__ b_conv,
        const float* __restrict__ b_gat, float* __restrict__ ws,
        float* __restrict__ out) {
    const int b = blockIdx.x, t = threadIdx.x;
    if (b == 256) {
        __shared__ float mc[DIN], mm[DIN];
        float sc = 0.f, sm = 0.f;
        for (int bb = 0; bb < 256; ++bb) sc += ws[WS_PARTC + bb * 256 + t];
        for (int bb = 0; bb < 64;  ++bb) sm += ws[WS_PARTM + bb * 256 + t];
        mc[t] = sc * (1.f / ND);
        mm[t] = sm * (1.f / NM);
        __syncthreads();
        if (t < OC) {
            const float4* wr = (const float4*)(W_conv + (size_t)t * DIN);
            float a = 0.f, m2 = 0.f;
#pragma unroll 8
            for (int v = 0; v < 64; ++v) {
                const float4 w = wr[v];
                const int ib = 4 * v;
                a  = fmaf(mc[ib], w.x, a);      a  = fmaf(mc[ib + 1], w.y, a);
                a  = fmaf(mc[ib + 2], w.z, a);  a  = fmaf(mc[ib + 3], w.w, a);
                m2 = fmaf(mm[ib], w.x, m2);     m2 = fmaf(mm[ib + 1], w.y, m2);
                m2 = fmaf(mm[ib + 2], w.z, m2); m2 = fmaf(mm[ib + 3], w.w, m2);
            }
            const float bc = b_conv[t];
            ws[WS_DIA + t] = a + bc;
            ws[WS_MED + t] = m2 + bc;
        }
        return;
    }
    __shared__ float zbuf[NE][8];   // logits -> z -> alpha
    __shared__ float anm[NM];
    __shared__ float ec[8][OC];
    anm[t]       = ws[WS_ANODE + ND + t];
    anm[t + 256] = ws[WS_ANODE + ND + 256 + t];
    __syncthreads();
    {
        const int r = t >> 5, l = t & 31;
        const int d = b * 8 + r;
        const float ah = ws[WS_AHE + d];
        const float an_d = ws[WS_ANODE + d];
        float lmax = -3.4e38f;
        for (int j = l; j < NE; j += 32) {
            const float v = (j == 0) ? an_d : anm[j - 1];
            const float lg = lrelu(v + ah);
            zbuf[j][r] = lg;
            lmax = fmaxf(lmax, lg);
        }
#pragma unroll
        for (int m = 1; m < 32; m <<= 1) lmax = fmaxf(lmax, __shfl_xor(lmax, m, 32));
        float ss = 0.f;
        for (int j = l; j < NE; j += 32) {
            const float z = __expf(zbuf[j][r] - lmax);
            zbuf[j][r] = z;
            ss += z;
        }
#pragma unroll
        for (int m = 1; m < 32; m <<= 1) ss += __shfl_xor(ss, m, 32);
        const float inv = 1.f / ss;
        if (l == 0) ws[WS_CD + d] = lmax + __logf(ss);   // for K3 alpha recompute
        for (int j = l; j < NE; j += 32) zbuf[j][r] *= inv;   // -> alpha
    }
    __syncthreads();
    const int o = t & (OC - 1), h = t >> 7;
    float acc[8] = {0, 0, 0, 0, 0, 0, 0, 0};
    const float* xm = ws + WS_XLIN + (size_t)ND * OC;
    for (int j = h * 256; j < h * 256 + 256; ++j) {
        const float xv = xm[(size_t)j * OC + o];
        const float4* zr = (const float4*)zbuf[j + 1];
        const float4 za = zr[0], zb4 = zr[1];
        acc[0] = fmaf(za.x,  xv, acc[0]);
        acc[1] = fmaf(za.y,  xv, acc[1]);
        acc[2] = fmaf(za.z,  xv, acc[2]);
        acc[3] = fmaf(za.w,  xv, acc[3]);
        acc[4] = fmaf(zb4.x, xv, acc[4]);
        acc[5] = fmaf(zb4.y, xv, acc[5]);
        acc[6] = fmaf(zb4.z, xv, acc[6]);
        acc[7] = fmaf(zb4.w, xv, acc[7]);
    }
    if (h == 1) {
#pragma unroll
        for (int k = 0; k < 8; ++k) ec[k][o] = acc[k];
    }
    __syncthreads();
    if (h == 0) {
        const float bg = b_gat[o];
#pragma unroll
        for (int k = 0; k < 8; ++k) {
            const int dd = b * 8 + k;
            const float a0 = zbuf[0][k];
            const float xown = ws[WS_XLIN + (size_t)dd * OC + o];
            const float ev = fmaf(a0, xown, acc[k] + ec[k][o]) * (1.f / NE);
            ws[WS_XLIN + (size_t)dd * OC + o] = ev;          // e in-place
            out[(size_t)dd * 2 * OC + o] = fmaf(a0, ev, bg); // dm half
        }
    }
}

// ---------------------------------------------------------------------------
// K3: blocks 0..63: 8 medicines each over all 2048 diseases, alpha staged in
//     LDS per 256-d chunk (e traffic: 64 blocks x 1 MB = 64 MB, was 256 MB).
//     blocks 64..127: dia_nf broadcast into disease rows' second half.
__global__ void __launch_bounds__(256) K3(
        const float* __restrict__ b_gat, const float* __restrict__ ws,
        float* __restrict__ out) {
    const int b = blockIdx.x, t = threadIdx.x;
    const int o = t & (OC - 1), h = t >> 7;
    if (b < 64) {
        __shared__ float zb[256][8];     // 8 KB per chunk
        __shared__ float ec2[8][OC];     // 4 KB
        __shared__ float anm8[8];
        const int m0 = b * 8;
        if (t < 8) anm8[t] = ws[WS_ANODE + ND + m0 + t];
        __syncthreads();
        float acc[8] = {0, 0, 0, 0, 0, 0, 0, 0};
        const float* e = ws + WS_XLIN;
        for (int c = 0; c < 8; ++c) {
            // stage alpha for this 256-d chunk
            for (int idx = t; idx < 2048; idx += 256) {
                const int dd = idx >> 3, mi = idx & 7;
                const int d = c * 256 + dd;
                zb[dd][mi] = __expf(lrelu(anm8[mi] + ws[WS_AHE + d]) - ws[WS_CD + d]);
            }
            __syncthreads();
            for (int dd = h * 128; dd < h * 128 + 128; ++dd) {
                const float ev = e[(size_t)(c * 256 + dd) * OC + o];
                const float4* zr = (const float4*)zb[dd];
                const float4 za = zr[0], zb4 = zr[1];
                acc[0] = fmaf(za.x,  ev, acc[0]);
                acc[1] = fmaf(za.y,  ev, acc[1]);
                acc[2] = fmaf(za.z,  ev, acc[2]);
                acc[3] = fmaf(za.w,  ev, acc[3]);
                acc[4] = fmaf(zb4.x, ev, acc[4]);
                acc[5] = fmaf(zb4.y, ev, acc[5]);
                acc[6] = fmaf(zb4.z, ev, acc[6]);
                acc[7] = fmaf(zb4.w, ev, acc[7]);
            }
            __syncthreads();
        }
        if (h == 1) {
#pragma unroll
            for (int k = 0; k < 8; ++k) ec2[k][o] = acc[k];
        }
        __syncthreads();
        if (h == 0) {
            const float bg = b_gat[o];
            const float mv = ws[WS_MED + o];
#pragma unroll
            for (int k = 0; k < 8; ++k) {
                const int m = m0 + k;
                out[(size_t)(ND + m) * 2 * OC + o]      = fmaf(acc[k] + ec2[k][o], 1.f / ND, bg);
                out[(size_t)(ND + m) * 2 * OC + OC + o] = mv;
            }
        }
    } else {
        const int q = b - 64;
        const float dv = ws[WS_DIA + o];
#pragma unroll
        for (int rr = 0; rr < 16; ++rr) {
            const int d = q * 32 + 2 * rr + h;
            out[(size_t)d * 2 * OC + OC + o] = dv;
        }
    }
}

extern "C" void kernel_launch(void* const* d_in, const int* in_sizes, int n_in,
                              void* d_out, int out_size, void* d_ws, size_t ws_size,
                              hipStream_t stream) {
    const float* c_emb   = (const float*)d_in[2];
    const float* m_emb   = (const float*)d_in[3];
    const float* W_conv  = (const float*)d_in[4];
    const float* b_conv  = (const float*)d_in[5];
    const float* W_gat   = (const float*)d_in[6];
    const float* att     = (const float*)d_in[7];
    const float* b_gat   = (const float*)d_in[8];
    const float* he_attr = (const float*)d_in[9];
    float* ws  = (float*)d_ws;
    float* out = (float*)d_out;

    hipLaunchKernelGGL(K1, dim3(384), dim3(256), 0, stream,
                       c_emb, m_emb, W_gat, att, he_attr, ws);
    hipLaunchKernelGGL(K2, dim3(257), dim3(256), 0, stream,
                       W_conv, b_conv, b_gat, ws, out);
    hipLaunchKernelGGL(K3, dim3(128), dim3(256), 0, stream, b_gat, ws, out);
}

// Round 18
// 131.830 us; speedup vs baseline: 2.6681x; 2.6681x over previous
//
#include <hip/hip_runtime.h>

#define ND 2048
#define NM 512
#define DIN 256
#define OC 128
#define NTOT 2560
#define NE 513      // slots per hyperedge

// Workspace float offsets. Dirty footprint ~1.6 MB (dirty ws slows the
// harness's 268 MB poison-fill — R14 evidence).
#define WS_PARTC 0                          // [256*256]
#define WS_PARTM (WS_PARTC + 256*256)       // [64*256]
#define WS_AHE   (WS_PARTM + 64*256)        // [2048]
#define WS_ANODE (WS_AHE + ND)              // [2560]
#define WS_CD    (WS_ANODE + NTOT)          // [2048]  C_d = M_d + ln(S_d)
#define WS_XLIN  (WS_CD + ND)               // [2560*128]; disease rows -> e in K2
#define WS_DIA   (WS_XLIN + NTOT*OC)        // [128]
#define WS_MED   (WS_DIA + OC)              // [128]

__device__ __forceinline__ float lrelu(float x) { return x > 0.f ? x : 0.2f * x; }

// ---------------------------------------------------------------------------
// K1: blocks 0..319: x_lin (8 rows) + a_node + mean partials.
//     blocks 320..383: w_e (redundant) + a_he (32 d's each).   [unchanged R17]
__global__ void __launch_bounds__(256) K1(
        const float* __restrict__ c_emb, const float* __restrict__ m_emb,
        const float* __restrict__ W_gat, const float* __restrict__ att,
        const float* __restrict__ he_attr, float* __restrict__ ws) {
    const int b = blockIdx.x, t = threadIdx.x;
    if (b < 320) {
        __shared__ float row[8][DIN];    // 8 KB
        __shared__ float sA[8][OC];      // 4 KB
        const int d0 = b * 8;
#pragma unroll
        for (int p = 0; p < 4; ++p) {
            const int idx = p * 256 + t;
            const int r = idx >> 7, c = idx & 127;
            const int d = d0 + r;
            const float* src = (d < ND) ? c_emb + (size_t)d * DIN
                                        : m_emb + (size_t)(d - ND) * DIN;
            const float2 u = ((const float2*)src)[c];
            row[r][2 * c]     = u.x;
            row[r][2 * c + 1] = u.y;
        }
        __syncthreads();
        {
            float pc = 0.f;
#pragma unroll
            for (int r = 0; r < 8; ++r) pc += row[r][t];
            if (b < 256) ws[WS_PARTC + b * 256 + t] = pc;
            else         ws[WS_PARTM + (b - 256) * 256 + t] = pc;
        }
        const int o = t & (OC - 1), h = t >> 7;
        float a0 = 0.f, a1 = 0.f, a2 = 0.f, a3 = 0.f;
        const float4* wr  = (const float4*)(W_gat + (size_t)o * DIN);
        const float4* r0v = (const float4*)(row[4 * h]);
        const float4* r1v = (const float4*)(row[4 * h + 1]);
        const float4* r2v = (const float4*)(row[4 * h + 2]);
        const float4* r3v = (const float4*)(row[4 * h + 3]);
#pragma unroll 4
        for (int v = 0; v < 64; ++v) {
            const float4 w  = wr[v];
            const float4 x0 = r0v[v], x1 = r1v[v], x2 = r2v[v], x3 = r3v[v];
            a0 = fmaf(x0.x, w.x, a0); a0 = fmaf(x0.y, w.y, a0);
            a0 = fmaf(x0.z, w.z, a0); a0 = fmaf(x0.w, w.w, a0);
            a1 = fmaf(x1.x, w.x, a1); a1 = fmaf(x1.y, w.y, a1);
            a1 = fmaf(x1.z, w.z, a1); a1 = fmaf(x1.w, w.w, a1);
            a2 = fmaf(x2.x, w.x, a2); a2 = fmaf(x2.y, w.y, a2);
            a2 = fmaf(x2.z, w.z, a2); a2 = fmaf(x2.w, w.w, a2);
            a3 = fmaf(x3.x, w.x, a3); a3 = fmaf(x3.y, w.y, a3);
            a3 = fmaf(x3.z, w.z, a3); a3 = fmaf(x3.w, w.w, a3);
        }
        float* xl = ws + WS_XLIN + (size_t)(d0 + 4 * h) * OC + o;
        xl[0 * OC] = a0; xl[1 * OC] = a1; xl[2 * OC] = a2; xl[3 * OC] = a3;
        const float at = att[o];
        sA[4 * h][o]     = a0 * at;
        sA[4 * h + 1][o] = a1 * at;
        sA[4 * h + 2][o] = a2 * at;
        sA[4 * h + 3][o] = a3 * at;
        __syncthreads();
#pragma unroll
        for (int st = 64; st >= 1; st >>= 1) {
            for (int idx = t; idx < 8 * st; idx += 256) {
                const int r = idx / st, i = idx - r * st;
                sA[r][i] += sA[r][i + st];
            }
            __syncthreads();
        }
        if (t < 8) ws[WS_ANODE + d0 + t] = sA[t][0];
    } else {
        __shared__ float satt[OC];
        __shared__ float we[DIN];
        const int q = b - 320;
        if (t < OC) satt[t] = att[OC + t];
        __syncthreads();
        float acc = 0.f;
#pragma unroll 8
        for (int o = 0; o < OC; ++o)
            acc = fmaf(W_gat[(size_t)o * DIN + t], satt[o], acc);
        we[t] = acc;
        __syncthreads();
        const int r = t >> 5, l = t & 31;
#pragma unroll
        for (int k = 0; k < 4; ++k) {
            const int d = q * 32 + k * 8 + r;
            const float* he = he_attr + (size_t)d * DIN;
            float ah = 0.f;
#pragma unroll
            for (int i = l; i < DIN; i += 32) ah = fmaf(he[i], we[i], ah);
#pragma unroll
            for (int m = 1; m < 32; m <<= 1) ah += __shfl_xor(ah, m, 32);
            if (l == 0) ws[WS_AHE + d] = ah;
        }
    }
}

// ---------------------------------------------------------------------------
// K2: blocks 0..255: softmax (8 d's) -> alpha, C_d; e in-place; disease dm half.
//     block 256: combine mean partials -> dia/med vectors.     [unchanged R17]
__global__ void __launch_bounds__(256) K2(
        const float* __restrict__ W_conv, const float* __restrict__ b_conv,
        const float* __restrict__ b_gat, float* __restrict__ ws,
        float* __restrict__ out) {
    const int b = blockIdx.x, t = threadIdx.x;
    if (b == 256) {
        __shared__ float mc[DIN], mm[DIN];
        float sc = 0.f, sm = 0.f;
        for (int bb = 0; bb < 256; ++bb) sc += ws[WS_PARTC + bb * 256 + t];
        for (int bb = 0; bb < 64;  ++bb) sm += ws[WS_PARTM + bb * 256 + t];
        mc[t] = sc * (1.f / ND);
        mm[t] = sm * (1.f / NM);
        __syncthreads();
        if (t < OC) {
            const float4* wr = (const float4*)(W_conv + (size_t)t * DIN);
            float a = 0.f, m2 = 0.f;
#pragma unroll 8
            for (int v = 0; v < 64; ++v) {
                const float4 w = wr[v];
                const int ib = 4 * v;
                a  = fmaf(mc[ib], w.x, a);      a  = fmaf(mc[ib + 1], w.y, a);
                a  = fmaf(mc[ib + 2], w.z, a);  a  = fmaf(mc[ib + 3], w.w, a);
                m2 = fmaf(mm[ib], w.x, m2);     m2 = fmaf(mm[ib + 1], w.y, m2);
                m2 = fmaf(mm[ib + 2], w.z, m2); m2 = fmaf(mm[ib + 3], w.w, m2);
            }
            const float bc = b_conv[t];
            ws[WS_DIA + t] = a + bc;
            ws[WS_MED + t] = m2 + bc;
        }
        return;
    }
    __shared__ float zbuf[NE][8];
    __shared__ float anm[NM];
    __shared__ float ec[8][OC];
    anm[t]       = ws[WS_ANODE + ND + t];
    anm[t + 256] = ws[WS_ANODE + ND + 256 + t];
    __syncthreads();
    {
        const int r = t >> 5, l = t & 31;
        const int d = b * 8 + r;
        const float ah = ws[WS_AHE + d];
        const float an_d = ws[WS_ANODE + d];
        float lmax = -3.4e38f;
        for (int j = l; j < NE; j += 32) {
            const float v = (j == 0) ? an_d : anm[j - 1];
            const float lg = lrelu(v + ah);
            zbuf[j][r] = lg;
            lmax = fmaxf(lmax, lg);
        }
#pragma unroll
        for (int m = 1; m < 32; m <<= 1) lmax = fmaxf(lmax, __shfl_xor(lmax, m, 32));
        float ss = 0.f;
        for (int j = l; j < NE; j += 32) {
            const float z = __expf(zbuf[j][r] - lmax);
            zbuf[j][r] = z;
            ss += z;
        }
#pragma unroll
        for (int m = 1; m < 32; m <<= 1) ss += __shfl_xor(ss, m, 32);
        const float inv = 1.f / ss;
        if (l == 0) ws[WS_CD + d] = lmax + __logf(ss);
        for (int j = l; j < NE; j += 32) zbuf[j][r] *= inv;   // -> alpha
    }
    __syncthreads();
    const int o = t & (OC - 1), h = t >> 7;
    float acc[8] = {0, 0, 0, 0, 0, 0, 0, 0};
    const float* xm = ws + WS_XLIN + (size_t)ND * OC;
    for (int j = h * 256; j < h * 256 + 256; ++j) {
        const float xv = xm[(size_t)j * OC + o];
        const float4* zr = (const float4*)zbuf[j + 1];
        const float4 za = zr[0], zb4 = zr[1];
        acc[0] = fmaf(za.x,  xv, acc[0]);
        acc[1] = fmaf(za.y,  xv, acc[1]);
        acc[2] = fmaf(za.z,  xv, acc[2]);
        acc[3] = fmaf(za.w,  xv, acc[3]);
        acc[4] = fmaf(zb4.x, xv, acc[4]);
        acc[5] = fmaf(zb4.y, xv, acc[5]);
        acc[6] = fmaf(zb4.z, xv, acc[6]);
        acc[7] = fmaf(zb4.w, xv, acc[7]);
    }
    if (h == 1) {
#pragma unroll
        for (int k = 0; k < 8; ++k) ec[k][o] = acc[k];
    }
    __syncthreads();
    if (h == 0) {
        const float bg = b_gat[o];
#pragma unroll
        for (int k = 0; k < 8; ++k) {
            const int dd = b * 8 + k;
            const float a0 = zbuf[0][k];
            const float xown = ws[WS_XLIN + (size_t)dd * OC + o];
            const float ev = fmaf(a0, xown, acc[k] + ec[k][o]) * (1.f / NE);
            ws[WS_XLIN + (size_t)dd * OC + o] = ev;
            out[(size_t)dd * 2 * OC + o] = fmaf(a0, ev, bg);
        }
    }
}

// ---------------------------------------------------------------------------
// K3: blocks 0..255: 2 medicines each, float4 e-loads, full parallelism.
//     blocks 256..319: dia_nf broadcast into disease rows' second half.
__global__ void __launch_bounds__(256) K3(
        const float* __restrict__ b_gat, const float* __restrict__ ws,
        float* __restrict__ out) {
    const int b = blockIdx.x, t = threadIdx.x;
    if (b < 256) {
        __shared__ float zb[ND][2];         // 16 KB alpha
        __shared__ float sacc[8][2][OC];    // 8 KB slice partials
        const int m0 = b * 2;
        const float an0 = ws[WS_ANODE + ND + m0];
        const float an1 = ws[WS_ANODE + ND + m0 + 1];
        for (int dd = t; dd < ND; dd += 256) {
            const float ahv = ws[WS_AHE + dd];
            const float cdv = ws[WS_CD + dd];
            zb[dd][0] = __expf(lrelu(an0 + ahv) - cdv);
            zb[dd][1] = __expf(lrelu(an1 + ahv) - cdv);
        }
        __syncthreads();
        // thread = (o-quad q, d-slice s): 256 independent float4 loads
        const int q = t & 31, s = t >> 5;
        const float4* e4 = (const float4*)(ws + WS_XLIN);
        float4 A0 = {0.f, 0.f, 0.f, 0.f}, A1 = {0.f, 0.f, 0.f, 0.f};
        const int dd0 = s * 256;
#pragma unroll 4
        for (int i = 0; i < 256; ++i) {
            const int dd = dd0 + i;
            const float4 ev = e4[(size_t)dd * 32 + q];
            const float z0 = zb[dd][0], z1 = zb[dd][1];
            A0.x = fmaf(z0, ev.x, A0.x);
            A0.y = fmaf(z0, ev.y, A0.y);
            A0.z = fmaf(z0, ev.z, A0.z);
            A0.w = fmaf(z0, ev.w, A0.w);
            A1.x = fmaf(z1, ev.x, A1.x);
            A1.y = fmaf(z1, ev.y, A1.y);
            A1.z = fmaf(z1, ev.z, A1.z);
            A1.w = fmaf(z1, ev.w, A1.w);
        }
        ((float4*)sacc[s][0])[q] = A0;
        ((float4*)sacc[s][1])[q] = A1;
        __syncthreads();
        // reduce 8 slices: thread t -> (med = t>>7, o = t&127)
        const int med = t >> 7, o = t & 127;
        float sum = 0.f;
#pragma unroll
        for (int sl = 0; sl < 8; ++sl) sum += sacc[sl][med][o];
        const int m = m0 + med;
        out[(size_t)(ND + m) * 2 * OC + o]      = fmaf(sum, 1.f / ND, b_gat[o]);
        out[(size_t)(ND + m) * 2 * OC + OC + o] = ws[WS_MED + o];
    } else {
        const int q2 = b - 256;
        const int o = t & (OC - 1), h = t >> 7;
        const float dv = ws[WS_DIA + o];
#pragma unroll
        for (int rr = 0; rr < 16; ++rr) {
            const int d = q2 * 32 + 2 * rr + h;
            out[(size_t)d * 2 * OC + OC + o] = dv;
        }
    }
}

extern "C" void kernel_launch(void* const* d_in, const int* in_sizes, int n_in,
                              void* d_out, int out_size, void* d_ws, size_t ws_size,
                              hipStream_t stream) {
    const float* c_emb   = (const float*)d_in[2];
    const float* m_emb   = (const float*)d_in[3];
    const float* W_conv  = (const float*)d_in[4];
    const float* b_conv  = (const float*)d_in[5];
    const float* W_gat   = (const float*)d_in[6];
    const float* att     = (const float*)d_in[7];
    const float* b_gat   = (const float*)d_in[8];
    const float* he_attr = (const float*)d_in[9];
    float* ws  = (float*)d_ws;
    float* out = (float*)d_out;

    hipLaunchKernelGGL(K1, dim3(384), dim3(256), 0, stream,
                       c_emb, m_emb, W_gat, att, he_attr, ws);
    hipLaunchKernelGGL(K2, dim3(257), dim3(256), 0, stream,
                       W_conv, b_conv, b_gat, ws, out);
    hipLaunchKernelGGL(K3, dim3(320), dim3(256), 0, stream, b_gat, ws, out);
}

// Round 19
// 128.491 us; speedup vs baseline: 2.7374x; 1.0260x over previous
//
#include <hip/hip_runtime.h>

#define ND 2048
#define NM 512
#define DIN 256
#define OC 128
#define NTOT 2560
#define NE 513      // slots per hyperedge

// Workspace float offsets. Dirty footprint ~1.6 MB (dirty ws slows the
// harness's 268 MB poison-fill — R14 evidence).
#define WS_PARTC 0                          // [256*256]
#define WS_PARTM (WS_PARTC + 256*256)       // [64*256]
#define WS_AHE   (WS_PARTM + 64*256)        // [2048]
#define WS_ANODE (WS_AHE + ND)              // [2560]
#define WS_CD    (WS_ANODE + NTOT)          // [2048]  C_d = M_d + ln(S_d)
#define WS_XLIN  (WS_CD + ND)               // [2560*128]; disease rows -> e in K2
#define WS_DIA   (WS_XLIN + NTOT*OC)        // [128]
#define WS_MED   (WS_DIA + OC)              // [128]

__device__ __forceinline__ float lrelu(float x) { return x > 0.f ? x : 0.2f * x; }

// ---------------------------------------------------------------------------
// K1: blocks 0..319: x_lin (8 rows) + a_node + mean partials.
//     blocks 320..383: w_e (redundant) + a_he (32 d's each).   [unchanged R18]
__global__ void __launch_bounds__(256) K1(
        const float* __restrict__ c_emb, const float* __restrict__ m_emb,
        const float* __restrict__ W_gat, const float* __restrict__ att,
        const float* __restrict__ he_attr, float* __restrict__ ws) {
    const int b = blockIdx.x, t = threadIdx.x;
    if (b < 320) {
        __shared__ float row[8][DIN];    // 8 KB
        __shared__ float sA[8][OC];      // 4 KB
        const int d0 = b * 8;
#pragma unroll
        for (int p = 0; p < 4; ++p) {
            const int idx = p * 256 + t;
            const int r = idx >> 7, c = idx & 127;
            const int d = d0 + r;
            const float* src = (d < ND) ? c_emb + (size_t)d * DIN
                                        : m_emb + (size_t)(d - ND) * DIN;
            const float2 u = ((const float2*)src)[c];
            row[r][2 * c]     = u.x;
            row[r][2 * c + 1] = u.y;
        }
        __syncthreads();
        {
            float pc = 0.f;
#pragma unroll
            for (int r = 0; r < 8; ++r) pc += row[r][t];
            if (b < 256) ws[WS_PARTC + b * 256 + t] = pc;
            else         ws[WS_PARTM + (b - 256) * 256 + t] = pc;
        }
        const int o = t & (OC - 1), h = t >> 7;
        float a0 = 0.f, a1 = 0.f, a2 = 0.f, a3 = 0.f;
        const float4* wr  = (const float4*)(W_gat + (size_t)o * DIN);
        const float4* r0v = (const float4*)(row[4 * h]);
        const float4* r1v = (const float4*)(row[4 * h + 1]);
        const float4* r2v = (const float4*)(row[4 * h + 2]);
        const float4* r3v = (const float4*)(row[4 * h + 3]);
#pragma unroll 4
        for (int v = 0; v < 64; ++v) {
            const float4 w  = wr[v];
            const float4 x0 = r0v[v], x1 = r1v[v], x2 = r2v[v], x3 = r3v[v];
            a0 = fmaf(x0.x, w.x, a0); a0 = fmaf(x0.y, w.y, a0);
            a0 = fmaf(x0.z, w.z, a0); a0 = fmaf(x0.w, w.w, a0);
            a1 = fmaf(x1.x, w.x, a1); a1 = fmaf(x1.y, w.y, a1);
            a1 = fmaf(x1.z, w.z, a1); a1 = fmaf(x1.w, w.w, a1);
            a2 = fmaf(x2.x, w.x, a2); a2 = fmaf(x2.y, w.y, a2);
            a2 = fmaf(x2.z, w.z, a2); a2 = fmaf(x2.w, w.w, a2);
            a3 = fmaf(x3.x, w.x, a3); a3 = fmaf(x3.y, w.y, a3);
            a3 = fmaf(x3.z, w.z, a3); a3 = fmaf(x3.w, w.w, a3);
        }
        float* xl = ws + WS_XLIN + (size_t)(d0 + 4 * h) * OC + o;
        xl[0 * OC] = a0; xl[1 * OC] = a1; xl[2 * OC] = a2; xl[3 * OC] = a3;
        const float at = att[o];
        sA[4 * h][o]     = a0 * at;
        sA[4 * h + 1][o] = a1 * at;
        sA[4 * h + 2][o] = a2 * at;
        sA[4 * h + 3][o] = a3 * at;
        __syncthreads();
#pragma unroll
        for (int st = 64; st >= 1; st >>= 1) {
            for (int idx = t; idx < 8 * st; idx += 256) {
                const int r = idx / st, i = idx - r * st;
                sA[r][i] += sA[r][i + st];
            }
            __syncthreads();
        }
        if (t < 8) ws[WS_ANODE + d0 + t] = sA[t][0];
    } else {
        __shared__ float satt[OC];
        __shared__ float we[DIN];
        const int q = b - 320;
        if (t < OC) satt[t] = att[OC + t];
        __syncthreads();
        float acc = 0.f;
#pragma unroll 8
        for (int o = 0; o < OC; ++o)
            acc = fmaf(W_gat[(size_t)o * DIN + t], satt[o], acc);
        we[t] = acc;
        __syncthreads();
        const int r = t >> 5, l = t & 31;
#pragma unroll
        for (int k = 0; k < 4; ++k) {
            const int d = q * 32 + k * 8 + r;
            const float* he = he_attr + (size_t)d * DIN;
            float ah = 0.f;
#pragma unroll
            for (int i = l; i < DIN; i += 32) ah = fmaf(he[i], we[i], ah);
#pragma unroll
            for (int m = 1; m < 32; m <<= 1) ah += __shfl_xor(ah, m, 32);
            if (l == 0) ws[WS_AHE + d] = ah;
        }
    }
}

// ---------------------------------------------------------------------------
// K2: blocks 0..255: softmax (8 d's) -> alpha, C_d; e in-place; disease dm half.
//     GEMM phase restructured: float4 Xm loads (R18-K3 lesson: scalar-load
//     chains at 1 wave/SIMD are latency-bound).
//     block 256: combine mean partials -> dia/med vectors.
__global__ void __launch_bounds__(256) K2(
        const float* __restrict__ W_conv, const float* __restrict__ b_conv,
        const float* __restrict__ b_gat, float* __restrict__ ws,
        float* __restrict__ out) {
    const int b = blockIdx.x, t = threadIdx.x;
    if (b == 256) {
        __shared__ float mc[DIN], mm[DIN];
        float sc = 0.f, sm = 0.f;
        for (int bb = 0; bb < 256; ++bb) sc += ws[WS_PARTC + bb * 256 + t];
        for (int bb = 0; bb < 64;  ++bb) sm += ws[WS_PARTM + bb * 256 + t];
        mc[t] = sc * (1.f / ND);
        mm[t] = sm * (1.f / NM);
        __syncthreads();
        if (t < OC) {
            const float4* wr = (const float4*)(W_conv + (size_t)t * DIN);
            float a = 0.f, m2 = 0.f;
#pragma unroll 8
            for (int v = 0; v < 64; ++v) {
                const float4 w = wr[v];
                const int ib = 4 * v;
                a  = fmaf(mc[ib], w.x, a);      a  = fmaf(mc[ib + 1], w.y, a);
                a  = fmaf(mc[ib + 2], w.z, a);  a  = fmaf(mc[ib + 3], w.w, a);
                m2 = fmaf(mm[ib], w.x, m2);     m2 = fmaf(mm[ib + 1], w.y, m2);
                m2 = fmaf(mm[ib + 2], w.z, m2); m2 = fmaf(mm[ib + 3], w.w, m2);
            }
            const float bc = b_conv[t];
            ws[WS_DIA + t] = a + bc;
            ws[WS_MED + t] = m2 + bc;
        }
        return;
    }
    __shared__ float zbuf[NE][8];        // 16.4 KB: logits -> z -> alpha
    __shared__ float anm[NM];            // 2 KB
    __shared__ float sacc[8][8][OC];     // 32 KB: [slice][k][o]
    anm[t]       = ws[WS_ANODE + ND + t];
    anm[t + 256] = ws[WS_ANODE + ND + 256 + t];
    __syncthreads();
    {
        const int r = t >> 5, l = t & 31;
        const int d = b * 8 + r;
        const float ah = ws[WS_AHE + d];
        const float an_d = ws[WS_ANODE + d];
        float lmax = -3.4e38f;
        for (int j = l; j < NE; j += 32) {
            const float v = (j == 0) ? an_d : anm[j - 1];
            const float lg = lrelu(v + ah);
            zbuf[j][r] = lg;
            lmax = fmaxf(lmax, lg);
        }
#pragma unroll
        for (int m = 1; m < 32; m <<= 1) lmax = fmaxf(lmax, __shfl_xor(lmax, m, 32));
        float ss = 0.f;
        for (int j = l; j < NE; j += 32) {
            const float z = __expf(zbuf[j][r] - lmax);
            zbuf[j][r] = z;
            ss += z;
        }
#pragma unroll
        for (int m = 1; m < 32; m <<= 1) ss += __shfl_xor(ss, m, 32);
        const float inv = 1.f / ss;
        if (l == 0) ws[WS_CD + d] = lmax + __logf(ss);
        for (int j = l; j < NE; j += 32) zbuf[j][r] *= inv;   // -> alpha
    }
    __syncthreads();
    // GEMM: thread = (o-quad q, j-slice s); 64 float4 loads per thread
    {
        const int q = t & 31, s = t >> 5;
        const float4* xm4 = (const float4*)(ws + WS_XLIN + (size_t)ND * OC);
        float4 acc[8];
#pragma unroll
        for (int k = 0; k < 8; ++k) acc[k] = make_float4(0.f, 0.f, 0.f, 0.f);
        const int j0 = s * 64;
#pragma unroll 4
        for (int i = 0; i < 64; ++i) {
            const int j = j0 + i;
            const float4 ev = xm4[(size_t)j * 32 + q];
            const float4* zr = (const float4*)zbuf[j + 1];
            const float4 za = zr[0], zb4 = zr[1];
            acc[0].x = fmaf(za.x, ev.x, acc[0].x); acc[0].y = fmaf(za.x, ev.y, acc[0].y);
            acc[0].z = fmaf(za.x, ev.z, acc[0].z); acc[0].w = fmaf(za.x, ev.w, acc[0].w);
            acc[1].x = fmaf(za.y, ev.x, acc[1].x); acc[1].y = fmaf(za.y, ev.y, acc[1].y);
            acc[1].z = fmaf(za.y, ev.z, acc[1].z); acc[1].w = fmaf(za.y, ev.w, acc[1].w);
            acc[2].x = fmaf(za.z, ev.x, acc[2].x); acc[2].y = fmaf(za.z, ev.y, acc[2].y);
            acc[2].z = fmaf(za.z, ev.z, acc[2].z); acc[2].w = fmaf(za.z, ev.w, acc[2].w);
            acc[3].x = fmaf(za.w, ev.x, acc[3].x); acc[3].y = fmaf(za.w, ev.y, acc[3].y);
            acc[3].z = fmaf(za.w, ev.z, acc[3].z); acc[3].w = fmaf(za.w, ev.w, acc[3].w);
            acc[4].x = fmaf(zb4.x, ev.x, acc[4].x); acc[4].y = fmaf(zb4.x, ev.y, acc[4].y);
            acc[4].z = fmaf(zb4.x, ev.z, acc[4].z); acc[4].w = fmaf(zb4.x, ev.w, acc[4].w);
            acc[5].x = fmaf(zb4.y, ev.x, acc[5].x); acc[5].y = fmaf(zb4.y, ev.y, acc[5].y);
            acc[5].z = fmaf(zb4.y, ev.z, acc[5].z); acc[5].w = fmaf(zb4.y, ev.w, acc[5].w);
            acc[6].x = fmaf(zb4.z, ev.x, acc[6].x); acc[6].y = fmaf(zb4.z, ev.y, acc[6].y);
            acc[6].z = fmaf(zb4.z, ev.z, acc[6].z); acc[6].w = fmaf(zb4.z, ev.w, acc[6].w);
            acc[7].x = fmaf(zb4.w, ev.x, acc[7].x); acc[7].y = fmaf(zb4.w, ev.y, acc[7].y);
            acc[7].z = fmaf(zb4.w, ev.z, acc[7].z); acc[7].w = fmaf(zb4.w, ev.w, acc[7].w);
        }
#pragma unroll
        for (int k = 0; k < 8; ++k) ((float4*)sacc[s][k])[q] = acc[k];
    }
    __syncthreads();
    // epilogue: 1024 (k,o) outputs over 256 threads
    {
        for (int idx = t; idx < 8 * OC; idx += 256) {
            const int k = idx >> 7, o = idx & 127;
            const int dd = b * 8 + k;
            float sum = 0.f;
#pragma unroll
            for (int s2 = 0; s2 < 8; ++s2) sum += sacc[s2][k][o];
            const float a0 = zbuf[0][k];
            const float xown = ws[WS_XLIN + (size_t)dd * OC + o];
            const float ev = fmaf(a0, xown, sum) * (1.f / NE);
            ws[WS_XLIN + (size_t)dd * OC + o] = ev;            // e in-place
            out[(size_t)dd * 2 * OC + o] = fmaf(a0, ev, b_gat[o]);
        }
    }
}

// ---------------------------------------------------------------------------
// K3: blocks 0..255: 2 medicines each, float4 e-loads.  [unchanged R18]
//     blocks 256..319: dia_nf broadcast into disease rows' second half.
__global__ void __launch_bounds__(256) K3(
        const float* __restrict__ b_gat, const float* __restrict__ ws,
        float* __restrict__ out) {
    const int b = blockIdx.x, t = threadIdx.x;
    if (b < 256) {
        __shared__ float zb[ND][2];         // 16 KB alpha
        __shared__ float sacc[8][2][OC];    // 8 KB slice partials
        const int m0 = b * 2;
        const float an0 = ws[WS_ANODE + ND + m0];
        const float an1 = ws[WS_ANODE + ND + m0 + 1];
        for (int dd = t; dd < ND; dd += 256) {
            const float ahv = ws[WS_AHE + dd];
            const float cdv = ws[WS_CD + dd];
            zb[dd][0] = __expf(lrelu(an0 + ahv) - cdv);
            zb[dd][1] = __expf(lrelu(an1 + ahv) - cdv);
        }
        __syncthreads();
        const int q = t & 31, s = t >> 5;
        const float4* e4 = (const float4*)(ws + WS_XLIN);
        float4 A0 = {0.f, 0.f, 0.f, 0.f}, A1 = {0.f, 0.f, 0.f, 0.f};
        const int dd0 = s * 256;
#pragma unroll 4
        for (int i = 0; i < 256; ++i) {
            const int dd = dd0 + i;
            const float4 ev = e4[(size_t)dd * 32 + q];
            const float z0 = zb[dd][0], z1 = zb[dd][1];
            A0.x = fmaf(z0, ev.x, A0.x);
            A0.y = fmaf(z0, ev.y, A0.y);
            A0.z = fmaf(z0, ev.z, A0.z);
            A0.w = fmaf(z0, ev.w, A0.w);
            A1.x = fmaf(z1, ev.x, A1.x);
            A1.y = fmaf(z1, ev.y, A1.y);
            A1.z = fmaf(z1, ev.z, A1.z);
            A1.w = fmaf(z1, ev.w, A1.w);
        }
        ((float4*)sacc[s][0])[q] = A0;
        ((float4*)sacc[s][1])[q] = A1;
        __syncthreads();
        const int med = t >> 7, o = t & 127;
        float sum = 0.f;
#pragma unroll
        for (int sl = 0; sl < 8; ++sl) sum += sacc[sl][med][o];
        const int m = m0 + med;
        out[(size_t)(ND + m) * 2 * OC + o]      = fmaf(sum, 1.f / ND, b_gat[o]);
        out[(size_t)(ND + m) * 2 * OC + OC + o] = ws[WS_MED + o];
    } else {
        const int q2 = b - 256;
        const int o = t & (OC - 1), h = t >> 7;
        const float dv = ws[WS_DIA + o];
#pragma unroll
        for (int rr = 0; rr < 16; ++rr) {
            const int d = q2 * 32 + 2 * rr + h;
            out[(size_t)d * 2 * OC + OC + o] = dv;
        }
    }
}

extern "C" void kernel_launch(void* const* d_in, const int* in_sizes, int n_in,
                              void* d_out, int out_size, void* d_ws, size_t ws_size,
                              hipStream_t stream) {
    const float* c_emb   = (const float*)d_in[2];
    const float* m_emb   = (const float*)d_in[3];
    const float* W_conv  = (const float*)d_in[4];
    const float* b_conv  = (const float*)d_in[5];
    const float* W_gat   = (const float*)d_in[6];
    const float* att     = (const float*)d_in[7];
    const float* b_gat   = (const float*)d_in[8];
    const float* he_attr = (const float*)d_in[9];
    float* ws  = (float*)d_ws;
    float* out = (float*)d_out;

    hipLaunchKernelGGL(K1, dim3(384), dim3(256), 0, stream,
                       c_emb, m_emb, W_gat, att, he_attr, ws);
    hipLaunchKernelGGL(K2, dim3(257), dim3(256), 0, stream,
                       W_conv, b_conv, b_gat, ws, out);
    hipLaunchKernelGGL(K3, dim3(320), dim3(256), 0, stream, b_gat, ws, out);
}

// Round 20
// 123.957 us; speedup vs baseline: 2.8375x; 1.0366x over previous
//
#include <hip/hip_runtime.h>

#define ND 2048
#define NM 512
#define DIN 256
#define OC 128
#define NTOT 2560
#define NE 513      // slots per hyperedge

// Workspace float offsets. Dirty footprint ~1.6 MB (dirty ws slows the
// harness's 268 MB poison-fill — R14 evidence).
#define WS_PARTC 0                          // [256*256]
#define WS_PARTM (WS_PARTC + 256*256)       // [64*256]
#define WS_AHE   (WS_PARTM + 64*256)        // [2048]
#define WS_ANODE (WS_AHE + ND)              // [2560]
#define WS_CD    (WS_ANODE + NTOT)          // [2048]  C_d = M_d + ln(S_d)
#define WS_XLIN  (WS_CD + ND)               // [2560*128] x_lin (f32, not overwritten)
#define WS_DIA   (WS_XLIN + NTOT*OC)        // [128]
#define WS_MED   (WS_DIA + OC)              // [128]
#define WS_E16   (WS_MED + OC)              // [2048*128 ushort = 131072 floats]

typedef unsigned short u16;
typedef unsigned int u32;

__device__ __forceinline__ float lrelu(float x) { return x > 0.f ? x : 0.2f * x; }
__device__ __forceinline__ u16 f2b(float f) {
    u32 x = __float_as_uint(f);
    return (u16)((x + 0x7fffu + ((x >> 16) & 1u)) >> 16);
}
__device__ __forceinline__ float bfl(u32 u) { return __uint_as_float(u << 16); }
__device__ __forceinline__ float bfh(u32 u) { return __uint_as_float(u & 0xffff0000u); }

// ---------------------------------------------------------------------------
// K1: blocks 0..319: x_lin (8 rows) + a_node + mean partials.
//     blocks 320..383: w_e (redundant) + a_he (32 d's each).   [unchanged R19]
__global__ void __launch_bounds__(256) K1(
        const float* __restrict__ c_emb, const float* __restrict__ m_emb,
        const float* __restrict__ W_gat, const float* __restrict__ att,
        const float* __restrict__ he_attr, float* __restrict__ ws) {
    const int b = blockIdx.x, t = threadIdx.x;
    if (b < 320) {
        __shared__ float row[8][DIN];
        __shared__ float sA[8][OC];
        const int d0 = b * 8;
#pragma unroll
        for (int p = 0; p < 4; ++p) {
            const int idx = p * 256 + t;
            const int r = idx >> 7, c = idx & 127;
            const int d = d0 + r;
            const float* src = (d < ND) ? c_emb + (size_t)d * DIN
                                        : m_emb + (size_t)(d - ND) * DIN;
            const float2 u = ((const float2*)src)[c];
            row[r][2 * c]     = u.x;
            row[r][2 * c + 1] = u.y;
        }
        __syncthreads();
        {
            float pc = 0.f;
#pragma unroll
            for (int r = 0; r < 8; ++r) pc += row[r][t];
            if (b < 256) ws[WS_PARTC + b * 256 + t] = pc;
            else         ws[WS_PARTM + (b - 256) * 256 + t] = pc;
        }
        const int o = t & (OC - 1), h = t >> 7;
        float a0 = 0.f, a1 = 0.f, a2 = 0.f, a3 = 0.f;
        const float4* wr  = (const float4*)(W_gat + (size_t)o * DIN);
        const float4* r0v = (const float4*)(row[4 * h]);
        const float4* r1v = (const float4*)(row[4 * h + 1]);
        const float4* r2v = (const float4*)(row[4 * h + 2]);
        const float4* r3v = (const float4*)(row[4 * h + 3]);
#pragma unroll 4
        for (int v = 0; v < 64; ++v) {
            const float4 w  = wr[v];
            const float4 x0 = r0v[v], x1 = r1v[v], x2 = r2v[v], x3 = r3v[v];
            a0 = fmaf(x0.x, w.x, a0); a0 = fmaf(x0.y, w.y, a0);
            a0 = fmaf(x0.z, w.z, a0); a0 = fmaf(x0.w, w.w, a0);
            a1 = fmaf(x1.x, w.x, a1); a1 = fmaf(x1.y, w.y, a1);
            a1 = fmaf(x1.z, w.z, a1); a1 = fmaf(x1.w, w.w, a1);
            a2 = fmaf(x2.x, w.x, a2); a2 = fmaf(x2.y, w.y, a2);
            a2 = fmaf(x2.z, w.z, a2); a2 = fmaf(x2.w, w.w, a2);
            a3 = fmaf(x3.x, w.x, a3); a3 = fmaf(x3.y, w.y, a3);
            a3 = fmaf(x3.z, w.z, a3); a3 = fmaf(x3.w, w.w, a3);
        }
        float* xl = ws + WS_XLIN + (size_t)(d0 + 4 * h) * OC + o;
        xl[0 * OC] = a0; xl[1 * OC] = a1; xl[2 * OC] = a2; xl[3 * OC] = a3;
        const float at = att[o];
        sA[4 * h][o]     = a0 * at;
        sA[4 * h + 1][o] = a1 * at;
        sA[4 * h + 2][o] = a2 * at;
        sA[4 * h + 3][o] = a3 * at;
        __syncthreads();
#pragma unroll
        for (int st = 64; st >= 1; st >>= 1) {
            for (int idx = t; idx < 8 * st; idx += 256) {
                const int r = idx / st, i = idx - r * st;
                sA[r][i] += sA[r][i + st];
            }
            __syncthreads();
        }
        if (t < 8) ws[WS_ANODE + d0 + t] = sA[t][0];
    } else {
        __shared__ float satt[OC];
        __shared__ float we[DIN];
        const int q = b - 320;
        if (t < OC) satt[t] = att[OC + t];
        __syncthreads();
        float acc = 0.f;
#pragma unroll 8
        for (int o = 0; o < OC; ++o)
            acc = fmaf(W_gat[(size_t)o * DIN + t], satt[o], acc);
        we[t] = acc;
        __syncthreads();
        const int r = t >> 5, l = t & 31;
#pragma unroll
        for (int k = 0; k < 4; ++k) {
            const int d = q * 32 + k * 8 + r;
            const float* he = he_attr + (size_t)d * DIN;
            float ah = 0.f;
#pragma unroll
            for (int i = l; i < DIN; i += 32) ah = fmaf(he[i], we[i], ah);
#pragma unroll
            for (int m = 1; m < 32; m <<= 1) ah += __shfl_xor(ah, m, 32);
            if (l == 0) ws[WS_AHE + d] = ah;
        }
    }
}

// ---------------------------------------------------------------------------
// K2: blocks 0..255: softmax (8 d's) -> alpha, C_d; e -> bf16 (WS_E16);
//     disease dm half. block 256: mean combine -> dia/med vectors.
__global__ void __launch_bounds__(256) K2(
        const float* __restrict__ W_conv, const float* __restrict__ b_conv,
        const float* __restrict__ b_gat, float* __restrict__ ws,
        float* __restrict__ out) {
    const int b = blockIdx.x, t = threadIdx.x;
    if (b == 256) {
        __shared__ float mc[DIN], mm[DIN];
        float sc = 0.f, sm = 0.f;
        for (int bb = 0; bb < 256; ++bb) sc += ws[WS_PARTC + bb * 256 + t];
        for (int bb = 0; bb < 64;  ++bb) sm += ws[WS_PARTM + bb * 256 + t];
        mc[t] = sc * (1.f / ND);
        mm[t] = sm * (1.f / NM);
        __syncthreads();
        if (t < OC) {
            const float4* wr = (const float4*)(W_conv + (size_t)t * DIN);
            float a = 0.f, m2 = 0.f;
#pragma unroll 8
            for (int v = 0; v < 64; ++v) {
                const float4 w = wr[v];
                const int ib = 4 * v;
                a  = fmaf(mc[ib], w.x, a);      a  = fmaf(mc[ib + 1], w.y, a);
                a  = fmaf(mc[ib + 2], w.z, a);  a  = fmaf(mc[ib + 3], w.w, a);
                m2 = fmaf(mm[ib], w.x, m2);     m2 = fmaf(mm[ib + 1], w.y, m2);
                m2 = fmaf(mm[ib + 2], w.z, m2); m2 = fmaf(mm[ib + 3], w.w, m2);
            }
            const float bc = b_conv[t];
            ws[WS_DIA + t] = a + bc;
            ws[WS_MED + t] = m2 + bc;
        }
        return;
    }
    __shared__ float zbuf[NE][8];
    __shared__ float anm[NM];
    __shared__ float sacc[8][8][OC];     // 32 KB [slice][k][o]
    anm[t]       = ws[WS_ANODE + ND + t];
    anm[t + 256] = ws[WS_ANODE + ND + 256 + t];
    __syncthreads();
    {
        const int r = t >> 5, l = t & 31;
        const int d = b * 8 + r;
        const float ah = ws[WS_AHE + d];
        const float an_d = ws[WS_ANODE + d];
        float lmax = -3.4e38f;
        for (int j = l; j < NE; j += 32) {
            const float v = (j == 0) ? an_d : anm[j - 1];
            const float lg = lrelu(v + ah);
            zbuf[j][r] = lg;
            lmax = fmaxf(lmax, lg);
        }
#pragma unroll
        for (int m = 1; m < 32; m <<= 1) lmax = fmaxf(lmax, __shfl_xor(lmax, m, 32));
        float ss = 0.f;
        for (int j = l; j < NE; j += 32) {
            const float z = __expf(zbuf[j][r] - lmax);
            zbuf[j][r] = z;
            ss += z;
        }
#pragma unroll
        for (int m = 1; m < 32; m <<= 1) ss += __shfl_xor(ss, m, 32);
        const float inv = 1.f / ss;
        if (l == 0) ws[WS_CD + d] = lmax + __logf(ss);
        for (int j = l; j < NE; j += 32) zbuf[j][r] *= inv;   // -> alpha
    }
    __syncthreads();
    // GEMM: thread = (o-quad q, j-slice s); 64 float4 loads per thread
    {
        const int q = t & 31, s = t >> 5;
        const float4* xm4 = (const float4*)(ws + WS_XLIN + (size_t)ND * OC);
        float4 acc[8];
#pragma unroll
        for (int k = 0; k < 8; ++k) acc[k] = make_float4(0.f, 0.f, 0.f, 0.f);
        const int j0 = s * 64;
#pragma unroll 4
        for (int i = 0; i < 64; ++i) {
            const int j = j0 + i;
            const float4 ev = xm4[(size_t)j * 32 + q];
            const float4* zr = (const float4*)zbuf[j + 1];
            const float4 za = zr[0], zb4 = zr[1];
            acc[0].x = fmaf(za.x, ev.x, acc[0].x); acc[0].y = fmaf(za.x, ev.y, acc[0].y);
            acc[0].z = fmaf(za.x, ev.z, acc[0].z); acc[0].w = fmaf(za.x, ev.w, acc[0].w);
            acc[1].x = fmaf(za.y, ev.x, acc[1].x); acc[1].y = fmaf(za.y, ev.y, acc[1].y);
            acc[1].z = fmaf(za.y, ev.z, acc[1].z); acc[1].w = fmaf(za.y, ev.w, acc[1].w);
            acc[2].x = fmaf(za.z, ev.x, acc[2].x); acc[2].y = fmaf(za.z, ev.y, acc[2].y);
            acc[2].z = fmaf(za.z, ev.z, acc[2].z); acc[2].w = fmaf(za.z, ev.w, acc[2].w);
            acc[3].x = fmaf(za.w, ev.x, acc[3].x); acc[3].y = fmaf(za.w, ev.y, acc[3].y);
            acc[3].z = fmaf(za.w, ev.z, acc[3].z); acc[3].w = fmaf(za.w, ev.w, acc[3].w);
            acc[4].x = fmaf(zb4.x, ev.x, acc[4].x); acc[4].y = fmaf(zb4.x, ev.y, acc[4].y);
            acc[4].z = fmaf(zb4.x, ev.z, acc[4].z); acc[4].w = fmaf(zb4.x, ev.w, acc[4].w);
            acc[5].x = fmaf(zb4.y, ev.x, acc[5].x); acc[5].y = fmaf(zb4.y, ev.y, acc[5].y);
            acc[5].z = fmaf(zb4.y, ev.z, acc[5].z); acc[5].w = fmaf(zb4.y, ev.w, acc[5].w);
            acc[6].x = fmaf(zb4.z, ev.x, acc[6].x); acc[6].y = fmaf(zb4.z, ev.y, acc[6].y);
            acc[6].z = fmaf(zb4.z, ev.z, acc[6].z); acc[6].w = fmaf(zb4.z, ev.w, acc[6].w);
            acc[7].x = fmaf(zb4.w, ev.x, acc[7].x); acc[7].y = fmaf(zb4.w, ev.y, acc[7].y);
            acc[7].z = fmaf(zb4.w, ev.z, acc[7].z); acc[7].w = fmaf(zb4.w, ev.w, acc[7].w);
        }
#pragma unroll
        for (int k = 0; k < 8; ++k) ((float4*)sacc[s][k])[q] = acc[k];
    }
    __syncthreads();
    // epilogue: e -> bf16 store; disease dm half
    {
        u16* e16 = (u16*)(ws + WS_E16);
        for (int idx = t; idx < 8 * OC; idx += 256) {
            const int k = idx >> 7, o = idx & 127;
            const int dd = b * 8 + k;
            float sum = 0.f;
#pragma unroll
            for (int s2 = 0; s2 < 8; ++s2) sum += sacc[s2][k][o];
            const float a0 = zbuf[0][k];
            const float xown = ws[WS_XLIN + (size_t)dd * OC + o];
            const float ev = fmaf(a0, xown, sum) * (1.f / NE);
            e16[(size_t)dd * OC + o] = f2b(ev);
            out[(size_t)dd * 2 * OC + o] = fmaf(a0, ev, b_gat[o]);
        }
    }
}

// ---------------------------------------------------------------------------
// K3: blocks 0..255: 2 medicines each; e read as bf16 (uint4 = 8 elems/load,
//     halves the 256 MB L3 broadcast). blocks 256..319: dia_nf broadcast.
__global__ void __launch_bounds__(256) K3(
        const float* __restrict__ b_gat, const float* __restrict__ ws,
        float* __restrict__ out) {
    const int b = blockIdx.x, t = threadIdx.x;
    if (b < 256) {
        __shared__ float zb[ND][2];          // 16 KB alpha
        __shared__ float sacc[16][2][OC];    // 16 KB slice partials
        const int m0 = b * 2;
        const float an0 = ws[WS_ANODE + ND + m0];
        const float an1 = ws[WS_ANODE + ND + m0 + 1];
        for (int dd = t; dd < ND; dd += 256) {
            const float ahv = ws[WS_AHE + dd];
            const float cdv = ws[WS_CD + dd];
            zb[dd][0] = __expf(lrelu(an0 + ahv) - cdv);
            zb[dd][1] = __expf(lrelu(an1 + ahv) - cdv);
        }
        __syncthreads();
        // thread = (o-oct q: 8 o's, d-slice s: 128 d's); 128 uint4 loads
        const int q = t & 15, s = t >> 4;
        const uint4* e4 = (const uint4*)((const u16*)(ws + WS_E16));
        float A0[8] = {0, 0, 0, 0, 0, 0, 0, 0};
        float A1[8] = {0, 0, 0, 0, 0, 0, 0, 0};
        const int dd0 = s * 128;
#pragma unroll 4
        for (int i = 0; i < 128; ++i) {
            const int dd = dd0 + i;
            const uint4 u = e4[(size_t)dd * 16 + q];
            const float z0 = zb[dd][0], z1 = zb[dd][1];
            const float e0 = bfl(u.x), e1 = bfh(u.x);
            const float e2 = bfl(u.y), e3 = bfh(u.y);
            const float e4v = bfl(u.z), e5 = bfh(u.z);
            const float e6 = bfl(u.w), e7 = bfh(u.w);
            A0[0] = fmaf(z0, e0, A0[0]); A0[1] = fmaf(z0, e1, A0[1]);
            A0[2] = fmaf(z0, e2, A0[2]); A0[3] = fmaf(z0, e3, A0[3]);
            A0[4] = fmaf(z0, e4v, A0[4]); A0[5] = fmaf(z0, e5, A0[5]);
            A0[6] = fmaf(z0, e6, A0[6]); A0[7] = fmaf(z0, e7, A0[7]);
            A1[0] = fmaf(z1, e0, A1[0]); A1[1] = fmaf(z1, e1, A1[1]);
            A1[2] = fmaf(z1, e2, A1[2]); A1[3] = fmaf(z1, e3, A1[3]);
            A1[4] = fmaf(z1, e4v, A1[4]); A1[5] = fmaf(z1, e5, A1[5]);
            A1[6] = fmaf(z1, e6, A1[6]); A1[7] = fmaf(z1, e7, A1[7]);
        }
#pragma unroll
        for (int i = 0; i < 8; ++i) {
            sacc[s][0][q * 8 + i] = A0[i];
            sacc[s][1][q * 8 + i] = A1[i];
        }
        __syncthreads();
        const int med = t >> 7, o = t & 127;
        float sum = 0.f;
#pragma unroll
        for (int sl = 0; sl < 16; ++sl) sum += sacc[sl][med][o];
        const int m = m0 + med;
        out[(size_t)(ND + m) * 2 * OC + o]      = fmaf(sum, 1.f / ND, b_gat[o]);
        out[(size_t)(ND + m) * 2 * OC + OC + o] = ws[WS_MED + o];
    } else {
        const int q2 = b - 256;
        const int o = t & (OC - 1), h = t >> 7;
        const float dv = ws[WS_DIA + o];
#pragma unroll
        for (int rr = 0; rr < 16; ++rr) {
            const int d = q2 * 32 + 2 * rr + h;
            out[(size_t)d * 2 * OC + OC + o] = dv;
        }
    }
}

extern "C" void kernel_launch(void* const* d_in, const int* in_sizes, int n_in,
                              void* d_out, int out_size, void* d_ws, size_t ws_size,
                              hipStream_t stream) {
    const float* c_emb   = (const float*)d_in[2];
    const float* m_emb   = (const float*)d_in[3];
    const float* W_conv  = (const float*)d_in[4];
    const float* b_conv  = (const float*)d_in[5];
    const float* W_gat   = (const float*)d_in[6];
    const float* att     = (const float*)d_in[7];
    const float* b_gat   = (const float*)d_in[8];
    const float* he_attr = (const float*)d_in[9];
    float* ws  = (float*)d_ws;
    float* out = (float*)d_out;

    hipLaunchKernelGGL(K1, dim3(384), dim3(256), 0, stream,
                       c_emb, m_emb, W_gat, att, he_attr, ws);
    hipLaunchKernelGGL(K2, dim3(257), dim3(256), 0, stream,
                       W_conv, b_conv, b_gat, ws, out);
    hipLaunchKernelGGL(K3, dim3(320), dim3(256), 0, stream, b_gat, ws, out);
}